// Round 2
// baseline (1644.783 us; speedup 1.0000x reference)
//
#include <hip/hip_runtime.h>
#include <hip/hip_bf16.h>

#define L_SEQ 2048
#define DM 1024
#define DI 2048
#define DS 128
#define NH 32
#define HD 64
#define DPROJ 4384
#define DPAD 4480
#define NBATCH 2
#define NCH 8
#define CH 256   // L_SEQ / NCH

typedef unsigned short u16;
typedef __attribute__((ext_vector_type(8))) short short8;
typedef __attribute__((ext_vector_type(4))) float f32x4;

__device__ __forceinline__ u16 f2bf(float f) {
  union { float f; unsigned u; } c; c.f = f;
  unsigned u = c.u;
  u += 0x7fffu + ((u >> 16) & 1u);
  return (u16)(u >> 16);
}

__device__ __forceinline__ float siluf(float x) {
  return x / (1.0f + expf(-x));
}

// ---------------- RMSNorm (f32 in -> bf16 out) ----------------
__global__ __launch_bounds__(256) void rmsnorm_kernel(
    const float* __restrict__ x, const float* __restrict__ w,
    u16* __restrict__ xnb) {
  int m = blockIdx.x;
  int t = threadIdx.x;
  const float* row = x + (size_t)m * DM;
  float4 v = *(const float4*)(row + t * 4);
  float ss = v.x * v.x + v.y * v.y + v.z * v.z + v.w * v.w;
#pragma unroll
  for (int o = 32; o > 0; o >>= 1) ss += __shfl_xor(ss, o);
  __shared__ float sred[4];
  if ((t & 63) == 0) sred[t >> 6] = ss;
  __syncthreads();
  ss = sred[0] + sred[1] + sred[2] + sred[3];
  float rs = rsqrtf(ss * (1.0f / DM) + 1e-6f);
  float4 wv = *(const float4*)(w + t * 4);
  ushort4 o;
  o.x = f2bf(v.x * rs * wv.x);
  o.y = f2bf(v.y * rs * wv.y);
  o.z = f2bf(v.z * rs * wv.z);
  o.w = f2bf(v.w * rs * wv.w);
  *(ushort4*)(xnb + (size_t)m * DM + t * 4) = o;
}

// ---------------- weight conversions ----------------
__global__ __launch_bounds__(256) void cvt_w1_kernel(
    const float* __restrict__ w, u16* __restrict__ o) {
  int r = blockIdx.x;          // 0..4479 (padded rows)
  int c = threadIdx.x * 4;
  ushort4 u;
  if (r < DPROJ) {
    float4 v = *(const float4*)(w + (size_t)r * DM + c);
    u.x = f2bf(v.x); u.y = f2bf(v.y); u.z = f2bf(v.z); u.w = f2bf(v.w);
  } else {
    u.x = 0; u.y = 0; u.z = 0; u.w = 0;
  }
  *(ushort4*)(o + (size_t)r * DM + c) = u;
}

__global__ __launch_bounds__(256) void cvt_w2_kernel(
    const float* __restrict__ w, u16* __restrict__ o) {
  size_t i = ((size_t)blockIdx.x * 256 + threadIdx.x) * 8;
  float4 v0 = *(const float4*)(w + i);
  float4 v1 = *(const float4*)(w + i + 4);
  ushort4 a, b;
  a.x = f2bf(v0.x); a.y = f2bf(v0.y); a.z = f2bf(v0.z); a.w = f2bf(v0.w);
  b.x = f2bf(v1.x); b.y = f2bf(v1.y); b.z = f2bf(v1.z); b.w = f2bf(v1.w);
  *(ushort4*)(o + i) = a;
  *(ushort4*)(o + i + 4) = b;
}

// ---------------- bf16 MFMA GEMM: C[m,n] = sum_k A[m,k]*B[n,k] (+resid) ----
// A: M x K bf16 row-major, Bw: N x K bf16 row-major, C: M x N f32 row-major.
__global__ __launch_bounds__(256, 2) void gemm_bt(
    const u16* __restrict__ A, const u16* __restrict__ Bw,
    float* __restrict__ C, const float* __restrict__ resid,
    int M, int N, int K) {
  __shared__ u16 lA[128 * 32];
  __shared__ u16 lB[128 * 32];
  const int tid = threadIdx.x;
  const int wv = tid >> 6, lane = tid & 63;
  const int wm = wv >> 1, wn = wv & 1;
  const int m0 = blockIdx.y * 128, n0 = blockIdx.x * 128;

  const int rowS = tid >> 2;              // 0..63
  const int colS = (tid & 3) * 8;         // ushort offset within 32-k row
  const u16* gA0 = A + (size_t)(m0 + rowS) * K + colS;
  const u16* gA1 = A + (size_t)(m0 + rowS + 64) * K + colS;
  const u16* gB0 = Bw + (size_t)(n0 + rowS) * K + colS;
  const u16* gB1 = Bw + (size_t)(n0 + rowS + 64) * K + colS;

  f32x4 acc[4][4] = {};
  short8 ra0 = *(const short8*)gA0;
  short8 ra1 = *(const short8*)gA1;
  short8 rb0 = *(const short8*)gB0;
  short8 rb1 = *(const short8*)gB1;

  const int nk = K >> 5;
  for (int kt = 0; kt < nk; ++kt) {
    __syncthreads();
    *(short8*)&lA[tid * 8] = ra0;
    *(short8*)&lA[2048 + tid * 8] = ra1;
    *(short8*)&lB[tid * 8] = rb0;
    *(short8*)&lB[2048 + tid * 8] = rb1;
    __syncthreads();
    if (kt + 1 < nk) {
      int ko = (kt + 1) << 5;
      ra0 = *(const short8*)(gA0 + ko);
      ra1 = *(const short8*)(gA1 + ko);
      rb0 = *(const short8*)(gB0 + ko);
      rb1 = *(const short8*)(gB1 + ko);
    }
    short8 af[4], bfr[4];
    const int r = lane & 15;
    const int koff = (lane >> 4) * 8;
#pragma unroll
    for (int i = 0; i < 4; ++i)
      af[i] = *(const short8*)&lA[(wm * 64 + i * 16 + r) * 32 + koff];
#pragma unroll
    for (int j = 0; j < 4; ++j)
      bfr[j] = *(const short8*)&lB[(wn * 64 + j * 16 + r) * 32 + koff];
#pragma unroll
    for (int i = 0; i < 4; ++i)
#pragma unroll
      for (int j = 0; j < 4; ++j)
        acc[i][j] = __builtin_amdgcn_mfma_f32_16x16x32_bf16(
            af[i], bfr[j], acc[i][j], 0, 0, 0);
  }

  const int rbase = m0 + wm * 64 + (lane >> 4) * 4;
  const int cbase = n0 + wn * 64 + (lane & 15);
#pragma unroll
  for (int i = 0; i < 4; ++i) {
#pragma unroll
    for (int j = 0; j < 4; ++j) {
      int row0 = rbase + i * 16;
      int col = cbase + j * 16;
#pragma unroll
      for (int rr = 0; rr < 4; ++rr) {
        size_t o = (size_t)(row0 + rr) * N + col;
        float v = acc[i][j][rr];
        if (resid) v += resid[o];
        C[o] = v;
      }
    }
  }
}

// ---------------- depthwise causal conv (K=4) + SiLU ----------------
__global__ __launch_bounds__(256) void conv_kernel(
    const float* __restrict__ proj, const float* __restrict__ cw,
    const float* __restrict__ cb, float* __restrict__ xh) {
  int m = blockIdx.x;            // b*L + l
  int l = m & (L_SEQ - 1);
  int c0 = threadIdx.x * 8;
  float4 wv[8];
#pragma unroll
  for (int j = 0; j < 8; ++j) wv[j] = *(const float4*)(cw + (size_t)(c0 + j) * 4);
  float acc[8];
#pragma unroll
  for (int j = 0; j < 8; ++j) acc[j] = cb[c0 + j];
#pragma unroll
  for (int k = 0; k < 4; ++k) {
    int lk = l + k - 3;
    if (lk >= 0) {
      const float* row = proj + (size_t)(m + k - 3) * DPAD + DI + c0;
      float4 r0 = *(const float4*)row;
      float4 r1 = *(const float4*)(row + 4);
      float rv[8] = {r0.x, r0.y, r0.z, r0.w, r1.x, r1.y, r1.z, r1.w};
#pragma unroll
      for (int j = 0; j < 8; ++j) {
        float wk = (k == 0) ? wv[j].x : (k == 1) ? wv[j].y : (k == 2) ? wv[j].z : wv[j].w;
        acc[j] = fmaf(rv[j], wk, acc[j]);
      }
    }
  }
  float4 o0, o1;
  o0.x = siluf(acc[0]); o0.y = siluf(acc[1]); o0.z = siluf(acc[2]); o0.w = siluf(acc[3]);
  o1.x = siluf(acc[4]); o1.y = siluf(acc[5]); o1.z = siluf(acc[6]); o1.w = siluf(acc[7]);
  float* out = xh + (size_t)m * DI + c0;
  *(float4*)out = o0;
  *(float4*)(out + 4) = o1;
}

// ---------------- dt / dA ----------------
__global__ __launch_bounds__(256) void dtda_kernel(
    const float* __restrict__ proj, const float* __restrict__ dt_bias,
    const float* __restrict__ A_log, float* __restrict__ dAdt) {
  int idx = blockIdx.x * 256 + threadIdx.x;   // m*32 + h
  int m = idx >> 5, h = idx & 31;
  float raw = proj[(size_t)m * DPAD + (2 * DI + 2 * DS) + h] + dt_bias[h];
  float dt = fmaxf(raw, 0.0f) + log1pf(expf(-fabsf(raw)));
  float dA = expf(-expf(A_log[h]) * dt);
  float2 o; o.x = dA; o.y = dt;
  *(float2*)(dAdt + (size_t)idx * 2) = o;
}

// ---------------- chunked selective scan ----------------
// 8192 waves: wid = ((b*32+h)*16 + pw)*8 + ch. lane = pg*16 + ng.
// Lane owns p = pw*4+pg (state rows), n-slice = ng*8..ng*8+8.

// Pass A: local scan from h=0, emit chunk-end state + decay product.
#define STATE_BODY(T, PB0, PB1, PXV, PAD)                                     \
  {                                                                           \
    int tn = (T) + 2;                                                         \
    if (t0 + tn > L_SEQ - 1) tn = L_SEQ - 1 - t0;                             \
    size_t ro = (size_t)tn * DPAD;                                            \
    float4 fB0 = PB0, fB1 = PB1;                                              \
    float fxv = PXV; float2 fad = PAD;                                        \
    PB0 = *(const float4*)(Bb + ro); PB1 = *(const float4*)(Bb + ro + 4);     \
    PXV = xb[(size_t)tn * DI]; PAD = *(const float2*)(ab + (size_t)tn * 64);  \
    float dA = fad.x; float dtx = fad.y * fxv;                                \
    hs0 = fmaf(hs0, dA, dtx * fB0.x);                                         \
    hs1 = fmaf(hs1, dA, dtx * fB0.y);                                         \
    hs2 = fmaf(hs2, dA, dtx * fB0.z);                                         \
    hs3 = fmaf(hs3, dA, dtx * fB0.w);                                         \
    hs4 = fmaf(hs4, dA, dtx * fB1.x);                                         \
    hs5 = fmaf(hs5, dA, dtx * fB1.y);                                         \
    hs6 = fmaf(hs6, dA, dtx * fB1.z);                                         \
    hs7 = fmaf(hs7, dA, dtx * fB1.w);                                         \
    prodA *= dA;                                                              \
  }

__global__ __launch_bounds__(256) void scan_state_kernel(
    const float* __restrict__ proj, const float* __restrict__ dAdt,
    const float* __restrict__ xhy, float* __restrict__ S,
    float* __restrict__ P) {
  int wid = (blockIdx.x << 2) + (threadIdx.x >> 6);  // 0..8191
  int lane = threadIdx.x & 63;
  int ng = lane & 15, pg = lane >> 4;
  int ch = wid & 7;
  int pw = (wid >> 3) & 15;
  int h  = (wid >> 7) & 31;
  int b  = wid >> 12;
  int p = pw * 4 + pg;
  int t0 = ch * CH;
  const float* Bb = proj + (size_t)(b * L_SEQ + t0) * DPAD + 2 * DI + ng * 8;
  const float* xb = xhy + (size_t)(b * L_SEQ + t0) * DI + h * HD + p;
  const float* ab = dAdt + (size_t)(b * L_SEQ + t0) * 64 + h * 2;

  float hs0 = 0, hs1 = 0, hs2 = 0, hs3 = 0, hs4 = 0, hs5 = 0, hs6 = 0, hs7 = 0;
  float prodA = 1.0f;

  float4 aB0 = *(const float4*)(Bb);
  float4 aB1 = *(const float4*)(Bb + 4);
  float axv = xb[0];
  float2 aad = *(const float2*)(ab);
  float4 bB0 = *(const float4*)(Bb + DPAD);
  float4 bB1 = *(const float4*)(Bb + DPAD + 4);
  float bxv = xb[DI];
  float2 bad = *(const float2*)(ab + 64);

  for (int t = 0; t < CH; t += 2) {
    STATE_BODY(t, aB0, aB1, axv, aad);
    STATE_BODY(t + 1, bB0, bB1, bxv, bad);
  }

  float* Sp = S + ((size_t)((b * 32 + h) * NCH + ch) * HD + p) * DS + ng * 8;
  float4 o0; o0.x = hs0; o0.y = hs1; o0.z = hs2; o0.w = hs3;
  float4 o1; o1.x = hs4; o1.y = hs5; o1.z = hs6; o1.w = hs7;
  *(float4*)Sp = o0;
  *(float4*)(Sp + 4) = o1;
  if (pw == 0 && lane == 0) P[(b * 32 + h) * NCH + ch] = prodA;
}

// Pass 2: sequential combine over chunks; S[c] becomes H0[c] (state BEFORE c).
__global__ __launch_bounds__(256) void combine_kernel(
    float* __restrict__ S, const float* __restrict__ P) {
  int tid = blockIdx.x * 256 + threadIdx.x;  // 0..524287
  int bh = tid >> 13, pn = tid & 8191;
  size_t base = (size_t)bh * NCH * 8192 + pn;
  float E = 0.0f;
#pragma unroll
  for (int c = 0; c < NCH; ++c) {
    size_t o = base + (size_t)c * 8192;
    float Sc = S[o];
    S[o] = E;
    E = fmaf(P[bh * NCH + c], E, Sc);
  }
}

// Pass B: scan within chunk starting from H0, write y (overwrites xh in place).
#define SCAN_BODY(T, PB0, PB1, PC0, PC1, PXV, PAD)                            \
  {                                                                           \
    int tn = (T) + 2;                                                         \
    if (t0 + tn > L_SEQ - 1) tn = L_SEQ - 1 - t0;                             \
    size_t ro = (size_t)tn * DPAD;                                            \
    float4 fB0 = PB0, fB1 = PB1, fC0 = PC0, fC1 = PC1;                        \
    float fxv = PXV; float2 fad = PAD;                                        \
    PB0 = *(const float4*)(Bb + ro); PB1 = *(const float4*)(Bb + ro + 4);     \
    PC0 = *(const float4*)(Cb + ro); PC1 = *(const float4*)(Cb + ro + 4);     \
    PXV = xb[(size_t)tn * DI]; PAD = *(const float2*)(ab + (size_t)tn * 64);  \
    float dA = fad.x; float dtx = fad.y * fxv; float acc;                     \
    hs0 = fmaf(hs0, dA, dtx * fB0.x); acc = hs0 * fC0.x;                      \
    hs1 = fmaf(hs1, dA, dtx * fB0.y); acc = fmaf(hs1, fC0.y, acc);            \
    hs2 = fmaf(hs2, dA, dtx * fB0.z); acc = fmaf(hs2, fC0.z, acc);            \
    hs3 = fmaf(hs3, dA, dtx * fB0.w); acc = fmaf(hs3, fC0.w, acc);            \
    hs4 = fmaf(hs4, dA, dtx * fB1.x); acc = fmaf(hs4, fC1.x, acc);            \
    hs5 = fmaf(hs5, dA, dtx * fB1.y); acc = fmaf(hs5, fC1.y, acc);            \
    hs6 = fmaf(hs6, dA, dtx * fB1.z); acc = fmaf(hs6, fC1.z, acc);            \
    hs7 = fmaf(hs7, dA, dtx * fB1.w); acc = fmaf(hs7, fC1.w, acc);            \
    acc += __shfl_xor(acc, 1);                                                \
    acc += __shfl_xor(acc, 2);                                                \
    acc += __shfl_xor(acc, 4);                                                \
    acc += __shfl_xor(acc, 8);                                                \
    if (ng == pg)                                                             \
      yw[(size_t)(T) * DI] = fmaf(Dh, fxv, acc);                              \
  }

__global__ __launch_bounds__(256) void scan_y_kernel(
    const float* __restrict__ proj, const float* __restrict__ dAdt,
    float* __restrict__ xhy, const float* __restrict__ Dv,
    const float* __restrict__ S) {
  int wid = (blockIdx.x << 2) + (threadIdx.x >> 6);  // 0..8191
  int lane = threadIdx.x & 63;
  int ng = lane & 15, pg = lane >> 4;
  int ch = wid & 7;
  int pw = (wid >> 3) & 15;
  int h  = (wid >> 7) & 31;
  int b  = wid >> 12;
  int p = pw * 4 + pg;
  int t0 = ch * CH;
  float Dh = Dv[h];
  const float* Bb = proj + (size_t)(b * L_SEQ + t0) * DPAD + 2 * DI + ng * 8;
  const float* Cb = Bb + DS;
  const float* xb = xhy + (size_t)(b * L_SEQ + t0) * DI + h * HD + p;
  float* yw = xhy + (size_t)(b * L_SEQ + t0) * DI + h * HD + p;
  const float* ab = dAdt + (size_t)(b * L_SEQ + t0) * 64 + h * 2;

  const float* Hp = S + ((size_t)((b * 32 + h) * NCH + ch) * HD + p) * DS + ng * 8;
  float4 h0a = *(const float4*)Hp;
  float4 h0b = *(const float4*)(Hp + 4);
  float hs0 = h0a.x, hs1 = h0a.y, hs2 = h0a.z, hs3 = h0a.w;
  float hs4 = h0b.x, hs5 = h0b.y, hs6 = h0b.z, hs7 = h0b.w;

  float4 aB0 = *(const float4*)(Bb);
  float4 aB1 = *(const float4*)(Bb + 4);
  float4 aC0 = *(const float4*)(Cb);
  float4 aC1 = *(const float4*)(Cb + 4);
  float axv = xb[0];
  float2 aad = *(const float2*)(ab);
  float4 bB0 = *(const float4*)(Bb + DPAD);
  float4 bB1 = *(const float4*)(Bb + DPAD + 4);
  float4 bC0 = *(const float4*)(Cb + DPAD);
  float4 bC1 = *(const float4*)(Cb + DPAD + 4);
  float bxv = xb[DI];
  float2 bad = *(const float2*)(ab + 64);

  for (int t = 0; t < CH; t += 2) {
    SCAN_BODY(t, aB0, aB1, aC0, aC1, axv, aad);
    SCAN_BODY(t + 1, bB0, bB1, bC0, bC1, bxv, bad);
  }
}

// ---------------- gating: yb = bf16(y * silu(z)) ----------------
__global__ __launch_bounds__(256) void gate_kernel(
    const float* __restrict__ xhy, const float* __restrict__ proj,
    u16* __restrict__ yb) {
  size_t i0 = ((size_t)blockIdx.x * 256 + threadIdx.x) * 8;
  size_t m = i0 >> 11;
  int c = (int)(i0 & 2047);
  float4 y0 = *(const float4*)(xhy + i0);
  float4 y1 = *(const float4*)(xhy + i0 + 4);
  const float* zp = proj + m * DPAD + c;
  float4 z0 = *(const float4*)zp;
  float4 z1 = *(const float4*)(zp + 4);
  ushort4 a, bq;
  a.x = f2bf(y0.x * siluf(z0.x));
  a.y = f2bf(y0.y * siluf(z0.y));
  a.z = f2bf(y0.z * siluf(z0.z));
  a.w = f2bf(y0.w * siluf(z0.w));
  bq.x = f2bf(y1.x * siluf(z1.x));
  bq.y = f2bf(y1.y * siluf(z1.y));
  bq.z = f2bf(y1.z * siluf(z1.z));
  bq.w = f2bf(y1.w * siluf(z1.w));
  *(ushort4*)(yb + i0) = a;
  *(ushort4*)(yb + i0 + 4) = bq;
}

extern "C" void kernel_launch(void* const* d_in, const int* in_sizes, int n_in,
                              void* d_out, int out_size, void* d_ws, size_t ws_size,
                              hipStream_t stream) {
  const float* x      = (const float*)d_in[0];
  const float* norm_w = (const float*)d_in[1];
  const float* w1     = (const float*)d_in[2];
  const float* cw     = (const float*)d_in[3];
  const float* cb     = (const float*)d_in[4];
  const float* A_log  = (const float*)d_in[5];
  const float* Dv     = (const float*)d_in[6];
  const float* dt_b   = (const float*)d_in[7];
  const float* w2     = (const float*)d_in[8];
  float* out = (float*)d_out;

  char* ws = (char*)d_ws;
  u16*   xnb  = (u16*)(ws);                    // 4096*1024*2      = 8,388,608
  u16*   w1b  = (u16*)(ws + 8388608);          // 4480*1024*2      = 9,175,040
  u16*   w2b  = (u16*)(ws + 17563648);         // 1024*2048*2      = 4,194,304
  float* proj = (float*)(ws + 21757952);       // 4096*4480*4      = 73,400,320
  float* xhy  = (float*)(ws + 95158272);       // 4096*2048*4      = 33,554,432
  float* dAdt = (float*)(ws + 128712704);      // 4096*32*2*4      = 1,048,576
  u16*   yb   = (u16*)(ws + 129761280);        // 4096*2048*2      = 16,777,216
  // S aliases yb (dead until gate); P aliases xnb head (dead after gemm1).
  float* S    = (float*)(ws + 129761280);      // 2*32*8*64*128*4  = 16,777,216
  float* P    = (float*)(ws);                  // 1024*4           = 4,096

  const int M = NBATCH * L_SEQ;  // 4096

  rmsnorm_kernel<<<M, 256, 0, stream>>>(x, norm_w, xnb);
  cvt_w1_kernel<<<DPAD, 256, 0, stream>>>(w1, w1b);
  cvt_w2_kernel<<<1024, 256, 0, stream>>>(w2, w2b);
  gemm_bt<<<dim3(DPAD / 128, M / 128), 256, 0, stream>>>(
      xnb, w1b, proj, nullptr, M, DPAD, DM);
  conv_kernel<<<M, 256, 0, stream>>>(proj, cw, cb, xhy);
  dtda_kernel<<<M * NH / 256, 256, 0, stream>>>(proj, dt_b, A_log, dAdt);
  scan_state_kernel<<<2048, 256, 0, stream>>>(proj, dAdt, xhy, S, P);
  combine_kernel<<<2048, 256, 0, stream>>>(S, P);
  scan_y_kernel<<<2048, 256, 0, stream>>>(proj, dAdt, xhy, Dv, S);
  gate_kernel<<<M * DI / 2048, 256, 0, stream>>>(xhy, proj, yb);
  gemm_bt<<<dim3(DM / 128, M / 128), 256, 0, stream>>>(
      yb, w2b, out, x, M, DM, DI);
}

// Round 3
// 508.482 us; speedup vs baseline: 3.2347x; 3.2347x over previous
//
#include <hip/hip_runtime.h>
#include <hip/hip_bf16.h>

#define L_SEQ 2048
#define DM 1024
#define DI 2048
#define DS 128
#define NH 32
#define HD 64
#define DPROJ 4384
#define DPAD 4480
#define NBATCH 2
#define NCH 8
#define CH 256   // L_SEQ / NCH
#define TT 32    // LDS time-tile

typedef unsigned short u16;
typedef __attribute__((ext_vector_type(8))) short short8;
typedef __attribute__((ext_vector_type(4))) float f32x4;

__device__ __forceinline__ u16 f2bf(float f) {
  union { float f; unsigned u; } c; c.f = f;
  unsigned u = c.u;
  u += 0x7fffu + ((u >> 16) & 1u);
  return (u16)(u >> 16);
}

__device__ __forceinline__ float siluf(float x) {
  return x / (1.0f + expf(-x));
}

// ---------------- RMSNorm (f32 in -> bf16 out) ----------------
__global__ __launch_bounds__(256) void rmsnorm_kernel(
    const float* __restrict__ x, const float* __restrict__ w,
    u16* __restrict__ xnb) {
  int m = blockIdx.x;
  int t = threadIdx.x;
  const float* row = x + (size_t)m * DM;
  float4 v = *(const float4*)(row + t * 4);
  float ss = v.x * v.x + v.y * v.y + v.z * v.z + v.w * v.w;
#pragma unroll
  for (int o = 32; o > 0; o >>= 1) ss += __shfl_xor(ss, o);
  __shared__ float sred[4];
  if ((t & 63) == 0) sred[t >> 6] = ss;
  __syncthreads();
  ss = sred[0] + sred[1] + sred[2] + sred[3];
  float rs = rsqrtf(ss * (1.0f / DM) + 1e-6f);
  float4 wv = *(const float4*)(w + t * 4);
  ushort4 o;
  o.x = f2bf(v.x * rs * wv.x);
  o.y = f2bf(v.y * rs * wv.y);
  o.z = f2bf(v.z * rs * wv.z);
  o.w = f2bf(v.w * rs * wv.w);
  *(ushort4*)(xnb + (size_t)m * DM + t * 4) = o;
}

// ---------------- weight conversions ----------------
__global__ __launch_bounds__(256) void cvt_w1_kernel(
    const float* __restrict__ w, u16* __restrict__ o) {
  int r = blockIdx.x;          // 0..4479 (padded rows)
  int c = threadIdx.x * 4;
  ushort4 u;
  if (r < DPROJ) {
    float4 v = *(const float4*)(w + (size_t)r * DM + c);
    u.x = f2bf(v.x); u.y = f2bf(v.y); u.z = f2bf(v.z); u.w = f2bf(v.w);
  } else {
    u.x = 0; u.y = 0; u.z = 0; u.w = 0;
  }
  *(ushort4*)(o + (size_t)r * DM + c) = u;
}

__global__ __launch_bounds__(256) void cvt_w2_kernel(
    const float* __restrict__ w, u16* __restrict__ o) {
  size_t i = ((size_t)blockIdx.x * 256 + threadIdx.x) * 8;
  float4 v0 = *(const float4*)(w + i);
  float4 v1 = *(const float4*)(w + i + 4);
  ushort4 a, b;
  a.x = f2bf(v0.x); a.y = f2bf(v0.y); a.z = f2bf(v0.z); a.w = f2bf(v0.w);
  b.x = f2bf(v1.x); b.y = f2bf(v1.y); b.z = f2bf(v1.z); b.w = f2bf(v1.w);
  *(ushort4*)(o + i) = a;
  *(ushort4*)(o + i + 4) = b;
}

// ---------------- bf16 MFMA GEMM: C[m,n] = sum_k A[m,k]*B[n,k] (+resid) ----
__global__ __launch_bounds__(256, 2) void gemm_bt(
    const u16* __restrict__ A, const u16* __restrict__ Bw,
    float* __restrict__ C, const float* __restrict__ resid,
    int M, int N, int K) {
  __shared__ u16 lA[128 * 32];
  __shared__ u16 lB[128 * 32];
  const int tid = threadIdx.x;
  const int wv = tid >> 6, lane = tid & 63;
  const int wm = wv >> 1, wn = wv & 1;
  const int m0 = blockIdx.y * 128, n0 = blockIdx.x * 128;

  const int rowS = tid >> 2;
  const int colS = (tid & 3) * 8;
  const u16* gA0 = A + (size_t)(m0 + rowS) * K + colS;
  const u16* gA1 = A + (size_t)(m0 + rowS + 64) * K + colS;
  const u16* gB0 = Bw + (size_t)(n0 + rowS) * K + colS;
  const u16* gB1 = Bw + (size_t)(n0 + rowS + 64) * K + colS;

  f32x4 acc[4][4] = {};
  short8 ra0 = *(const short8*)gA0;
  short8 ra1 = *(const short8*)gA1;
  short8 rb0 = *(const short8*)gB0;
  short8 rb1 = *(const short8*)gB1;

  const int nk = K >> 5;
  for (int kt = 0; kt < nk; ++kt) {
    __syncthreads();
    *(short8*)&lA[tid * 8] = ra0;
    *(short8*)&lA[2048 + tid * 8] = ra1;
    *(short8*)&lB[tid * 8] = rb0;
    *(short8*)&lB[2048 + tid * 8] = rb1;
    __syncthreads();
    if (kt + 1 < nk) {
      int ko = (kt + 1) << 5;
      ra0 = *(const short8*)(gA0 + ko);
      ra1 = *(const short8*)(gA1 + ko);
      rb0 = *(const short8*)(gB0 + ko);
      rb1 = *(const short8*)(gB1 + ko);
    }
    short8 af[4], bfr[4];
    const int r = lane & 15;
    const int koff = (lane >> 4) * 8;
#pragma unroll
    for (int i = 0; i < 4; ++i)
      af[i] = *(const short8*)&lA[(wm * 64 + i * 16 + r) * 32 + koff];
#pragma unroll
    for (int j = 0; j < 4; ++j)
      bfr[j] = *(const short8*)&lB[(wn * 64 + j * 16 + r) * 32 + koff];
#pragma unroll
    for (int i = 0; i < 4; ++i)
#pragma unroll
      for (int j = 0; j < 4; ++j)
        acc[i][j] = __builtin_amdgcn_mfma_f32_16x16x32_bf16(
            af[i], bfr[j], acc[i][j], 0, 0, 0);
  }

  const int rbase = m0 + wm * 64 + (lane >> 4) * 4;
  const int cbase = n0 + wn * 64 + (lane & 15);
#pragma unroll
  for (int i = 0; i < 4; ++i) {
#pragma unroll
    for (int j = 0; j < 4; ++j) {
      int row0 = rbase + i * 16;
      int col = cbase + j * 16;
#pragma unroll
      for (int rr = 0; rr < 4; ++rr) {
        size_t o = (size_t)(row0 + rr) * N + col;
        float v = acc[i][j][rr];
        if (resid) v += resid[o];
        C[o] = v;
      }
    }
  }
}

// ---------------- depthwise causal conv (K=4) + SiLU ----------------
__global__ __launch_bounds__(256) void conv_kernel(
    const float* __restrict__ proj, const float* __restrict__ cw,
    const float* __restrict__ cb, float* __restrict__ xh) {
  int m = blockIdx.x;            // b*L + l
  int l = m & (L_SEQ - 1);
  int c0 = threadIdx.x * 8;
  float4 wv[8];
#pragma unroll
  for (int j = 0; j < 8; ++j) wv[j] = *(const float4*)(cw + (size_t)(c0 + j) * 4);
  float acc[8];
#pragma unroll
  for (int j = 0; j < 8; ++j) acc[j] = cb[c0 + j];
#pragma unroll
  for (int k = 0; k < 4; ++k) {
    int lk = l + k - 3;
    if (lk >= 0) {
      const float* row = proj + (size_t)(m + k - 3) * DPAD + DI + c0;
      float4 r0 = *(const float4*)row;
      float4 r1 = *(const float4*)(row + 4);
      float rv[8] = {r0.x, r0.y, r0.z, r0.w, r1.x, r1.y, r1.z, r1.w};
#pragma unroll
      for (int j = 0; j < 8; ++j) {
        float wk = (k == 0) ? wv[j].x : (k == 1) ? wv[j].y : (k == 2) ? wv[j].z : wv[j].w;
        acc[j] = fmaf(rv[j], wk, acc[j]);
      }
    }
  }
  float4 o0, o1;
  o0.x = siluf(acc[0]); o0.y = siluf(acc[1]); o0.z = siluf(acc[2]); o0.w = siluf(acc[3]);
  o1.x = siluf(acc[4]); o1.y = siluf(acc[5]); o1.z = siluf(acc[6]); o1.w = siluf(acc[7]);
  float* out = xh + (size_t)m * DI + c0;
  *(float4*)out = o0;
  *(float4*)(out + 4) = o1;
}

// ---------------- dt / dA ----------------
__global__ __launch_bounds__(256) void dtda_kernel(
    const float* __restrict__ proj, const float* __restrict__ dt_bias,
    const float* __restrict__ A_log, float* __restrict__ dAdt) {
  int idx = blockIdx.x * 256 + threadIdx.x;   // m*32 + h
  int m = idx >> 5, h = idx & 31;
  float raw = proj[(size_t)m * DPAD + (2 * DI + 2 * DS) + h] + dt_bias[h];
  float dt = fmaxf(raw, 0.0f) + log1pf(expf(-fabsf(raw)));
  float dA = expf(-expf(A_log[h]) * dt);
  float2 o; o.x = dA; o.y = dt;
  *(float2*)(dAdt + (size_t)idx * 2) = o;
}

// ---------------- chunked selective scan, LDS-staged ----------------
// 512 blocks of 1024 threads; block = (b, h, ch). Thread owns p = tid>>4,
// n-slice = (tid&15)*8..+8 (8 f32 state regs). Per 32-step tile: bulk
// coalesced global->reg->LDS staging (reg double-buffer), scan from LDS.

// Pass A: local scan from h=0; emit chunk-end state + chunk decay product.
__global__ __launch_bounds__(1024) void scan_state_kernel(
    const float* __restrict__ proj, const float* __restrict__ dAdt,
    const float* __restrict__ xhy, float* __restrict__ S,
    float* __restrict__ P) {
  __shared__ float sB[TT][DS];     // 16 KB
  __shared__ float sX[TT][HD];     // 8 KB
  __shared__ float2 sAD[TT];       // 256 B
  const int bid = blockIdx.x;
  const int ch = bid & 7, h = (bid >> 3) & 31, b = bid >> 8;
  const int t0 = ch * CH;
  const int tid = threadIdx.x;
  const int p = tid >> 4, ng = tid & 15;
  const size_t mbase = (size_t)(b * L_SEQ + t0);

  // staging index maps
  const int brow = tid >> 5, bcol = (tid & 31) * 4;      // 1024 f4 = 32x128
  const int xrow = tid >> 4, xcol = (tid & 15) * 4;      // 512 f4  = 32x64

  float hs0 = 0, hs1 = 0, hs2 = 0, hs3 = 0, hs4 = 0, hs5 = 0, hs6 = 0, hs7 = 0;
  float prodA = 1.0f;

  float4 rB, rX; float2 rAD;
  rB = *(const float4*)(proj + (mbase + brow) * DPAD + 2 * DI + bcol);
  if (tid < 512) rX = *(const float4*)(xhy + (mbase + xrow) * DI + h * HD + xcol);
  if (tid < 32)  rAD = *(const float2*)(dAdt + (mbase + tid) * 64 + h * 2);

  for (int tt = 0; tt < CH; tt += TT) {
    __syncthreads();
    *(float4*)&sB[brow][bcol] = rB;
    if (tid < 512) *(float4*)&sX[xrow][xcol] = rX;
    if (tid < 32)  sAD[tid] = rAD;
    __syncthreads();
    if (tt + TT < CH) {
      size_t mb2 = mbase + tt + TT;
      rB = *(const float4*)(proj + (mb2 + brow) * DPAD + 2 * DI + bcol);
      if (tid < 512) rX = *(const float4*)(xhy + (mb2 + xrow) * DI + h * HD + xcol);
      if (tid < 32)  rAD = *(const float2*)(dAdt + (mb2 + tid) * 64 + h * 2);
    }
#pragma unroll
    for (int t = 0; t < TT; ++t) {
      float2 ad = sAD[t];
      float xv = sX[t][p];
      float dA = ad.x;
      float dtx = ad.y * xv;
      const float* Bp = &sB[t][ng * 8];
      float4 B0 = *(const float4*)Bp;
      float4 B1 = *(const float4*)(Bp + 4);
      hs0 = fmaf(hs0, dA, dtx * B0.x);
      hs1 = fmaf(hs1, dA, dtx * B0.y);
      hs2 = fmaf(hs2, dA, dtx * B0.z);
      hs3 = fmaf(hs3, dA, dtx * B0.w);
      hs4 = fmaf(hs4, dA, dtx * B1.x);
      hs5 = fmaf(hs5, dA, dtx * B1.y);
      hs6 = fmaf(hs6, dA, dtx * B1.z);
      hs7 = fmaf(hs7, dA, dtx * B1.w);
      prodA *= dA;
    }
  }

  float* Sp = S + ((size_t)((b * 32 + h) * NCH + ch) * HD + p) * DS + ng * 8;
  float4 o0; o0.x = hs0; o0.y = hs1; o0.z = hs2; o0.w = hs3;
  float4 o1; o1.x = hs4; o1.y = hs5; o1.z = hs6; o1.w = hs7;
  *(float4*)Sp = o0;
  *(float4*)(Sp + 4) = o1;
  if (tid == 0) P[(b * 32 + h) * NCH + ch] = prodA;
}

// Pass 2: sequential combine over chunks; S[c] becomes H0[c] (state BEFORE c).
__global__ __launch_bounds__(256) void combine_kernel(
    float* __restrict__ S, const float* __restrict__ P) {
  int tid = blockIdx.x * 256 + threadIdx.x;  // 0..524287
  int bh = tid >> 13, pn = tid & 8191;
  size_t base = (size_t)bh * NCH * 8192 + pn;
  float E = 0.0f;
#pragma unroll
  for (int c = 0; c < NCH; ++c) {
    size_t o = base + (size_t)c * 8192;
    float Sc = S[o];
    S[o] = E;
    E = fmaf(P[bh * NCH + c], E, Sc);
  }
}

// Pass B: scan within chunk starting from H0; write y (in place over xh).
__global__ __launch_bounds__(1024) void scan_y_kernel(
    const float* __restrict__ proj, const float* __restrict__ dAdt,
    float* __restrict__ xhy, const float* __restrict__ Dv,
    const float* __restrict__ S) {
  __shared__ float sBC[TT][2 * DS];  // 32 KB  (B | C per row)
  __shared__ float sX[TT][HD];       // 8 KB
  __shared__ float sY[TT][HD];       // 8 KB
  __shared__ float2 sAD[TT];         // 256 B
  const int bid = blockIdx.x;
  const int ch = bid & 7, h = (bid >> 3) & 31, b = bid >> 8;
  const int t0 = ch * CH;
  const int tid = threadIdx.x;
  const int p = tid >> 4, ng = tid & 15;
  const size_t mbase = (size_t)(b * L_SEQ + t0);
  const float Dh = Dv[h];

  // staging index maps: BC = 2048 f4 (2 per thread), X/Y = 512 f4
  const int crow0 = tid >> 6, ccol0 = (tid & 63) * 4;          // rows 0..15
  const int crow1 = 16 + (tid >> 6), ccol1 = ccol0;            // rows 16..31
  const int xrow = tid >> 4, xcol = (tid & 15) * 4;

  // initial state H0
  const float* Hp = S + ((size_t)((b * 32 + h) * NCH + ch) * HD + p) * DS + ng * 8;
  float4 h0a = *(const float4*)Hp;
  float4 h0b = *(const float4*)(Hp + 4);
  float hs0 = h0a.x, hs1 = h0a.y, hs2 = h0a.z, hs3 = h0a.w;
  float hs4 = h0b.x, hs5 = h0b.y, hs6 = h0b.z, hs7 = h0b.w;

  float4 rC0, rC1, rX; float2 rAD;
  rC0 = *(const float4*)(proj + (mbase + crow0) * DPAD + 2 * DI + ccol0);
  rC1 = *(const float4*)(proj + (mbase + crow1) * DPAD + 2 * DI + ccol1);
  if (tid < 512) rX = *(const float4*)(xhy + (mbase + xrow) * DI + h * HD + xcol);
  if (tid < 32)  rAD = *(const float2*)(dAdt + (mbase + tid) * 64 + h * 2);

  for (int tt = 0; tt < CH; tt += TT) {
    __syncthreads();
    *(float4*)&sBC[crow0][ccol0] = rC0;
    *(float4*)&sBC[crow1][ccol1] = rC1;
    if (tid < 512) *(float4*)&sX[xrow][xcol] = rX;
    if (tid < 32)  sAD[tid] = rAD;
    __syncthreads();
    if (tt + TT < CH) {
      size_t mb2 = mbase + tt + TT;
      rC0 = *(const float4*)(proj + (mb2 + crow0) * DPAD + 2 * DI + ccol0);
      rC1 = *(const float4*)(proj + (mb2 + crow1) * DPAD + 2 * DI + ccol1);
      if (tid < 512) rX = *(const float4*)(xhy + (mb2 + xrow) * DI + h * HD + xcol);
      if (tid < 32)  rAD = *(const float2*)(dAdt + (mb2 + tid) * 64 + h * 2);
    }
#pragma unroll
    for (int t = 0; t < TT; ++t) {
      float2 ad = sAD[t];
      float xv = sX[t][p];
      float dA = ad.x;
      float dtx = ad.y * xv;
      const float* Bp = &sBC[t][ng * 8];
      const float* Cp = &sBC[t][DS + ng * 8];
      float4 B0 = *(const float4*)Bp;
      float4 B1 = *(const float4*)(Bp + 4);
      float4 C0 = *(const float4*)Cp;
      float4 C1 = *(const float4*)(Cp + 4);
      float acc;
      hs0 = fmaf(hs0, dA, dtx * B0.x); acc = hs0 * C0.x;
      hs1 = fmaf(hs1, dA, dtx * B0.y); acc = fmaf(hs1, C0.y, acc);
      hs2 = fmaf(hs2, dA, dtx * B0.z); acc = fmaf(hs2, C0.z, acc);
      hs3 = fmaf(hs3, dA, dtx * B0.w); acc = fmaf(hs3, C0.w, acc);
      hs4 = fmaf(hs4, dA, dtx * B1.x); acc = fmaf(hs4, C1.x, acc);
      hs5 = fmaf(hs5, dA, dtx * B1.y); acc = fmaf(hs5, C1.y, acc);
      hs6 = fmaf(hs6, dA, dtx * B1.z); acc = fmaf(hs6, C1.z, acc);
      hs7 = fmaf(hs7, dA, dtx * B1.w); acc = fmaf(hs7, C1.w, acc);
      acc += __shfl_xor(acc, 1);
      acc += __shfl_xor(acc, 2);
      acc += __shfl_xor(acc, 4);
      acc += __shfl_xor(acc, 8);
      if (ng == 0) sY[t][p] = fmaf(Dh, xv, acc);
    }
    __syncthreads();
    if (tid < 512) {
      float4 yv = *(const float4*)&sY[xrow][xcol];
      *(float4*)(xhy + (mbase + tt + xrow) * DI + h * HD + xcol) = yv;
    }
  }
}

// ---------------- gating: yb = bf16(y * silu(z)) ----------------
__global__ __launch_bounds__(256) void gate_kernel(
    const float* __restrict__ xhy, const float* __restrict__ proj,
    u16* __restrict__ yb) {
  size_t i0 = ((size_t)blockIdx.x * 256 + threadIdx.x) * 8;
  size_t m = i0 >> 11;
  int c = (int)(i0 & 2047);
  float4 y0 = *(const float4*)(xhy + i0);
  float4 y1 = *(const float4*)(xhy + i0 + 4);
  const float* zp = proj + m * DPAD + c;
  float4 z0 = *(const float4*)zp;
  float4 z1 = *(const float4*)(zp + 4);
  ushort4 a, bq;
  a.x = f2bf(y0.x * siluf(z0.x));
  a.y = f2bf(y0.y * siluf(z0.y));
  a.z = f2bf(y0.z * siluf(z0.z));
  a.w = f2bf(y0.w * siluf(z0.w));
  bq.x = f2bf(y1.x * siluf(z1.x));
  bq.y = f2bf(y1.y * siluf(z1.y));
  bq.z = f2bf(y1.z * siluf(z1.z));
  bq.w = f2bf(y1.w * siluf(z1.w));
  *(ushort4*)(yb + i0) = a;
  *(ushort4*)(yb + i0 + 4) = bq;
}

extern "C" void kernel_launch(void* const* d_in, const int* in_sizes, int n_in,
                              void* d_out, int out_size, void* d_ws, size_t ws_size,
                              hipStream_t stream) {
  const float* x      = (const float*)d_in[0];
  const float* norm_w = (const float*)d_in[1];
  const float* w1     = (const float*)d_in[2];
  const float* cw     = (const float*)d_in[3];
  const float* cb     = (const float*)d_in[4];
  const float* A_log  = (const float*)d_in[5];
  const float* Dv     = (const float*)d_in[6];
  const float* dt_b   = (const float*)d_in[7];
  const float* w2     = (const float*)d_in[8];
  float* out = (float*)d_out;

  char* ws = (char*)d_ws;
  u16*   xnb  = (u16*)(ws);                    // 4096*1024*2      = 8,388,608
  u16*   w1b  = (u16*)(ws + 8388608);          // 4480*1024*2      = 9,175,040
  u16*   w2b  = (u16*)(ws + 17563648);         // 1024*2048*2      = 4,194,304
  float* proj = (float*)(ws + 21757952);       // 4096*4480*4      = 73,400,320
  float* xhy  = (float*)(ws + 95158272);       // 4096*2048*4      = 33,554,432
  float* dAdt = (float*)(ws + 128712704);      // 4096*32*2*4      = 1,048,576
  u16*   yb   = (u16*)(ws + 129761280);        // 4096*2048*2      = 16,777,216
  // S aliases yb (dead until gate); P aliases xnb head (dead after gemm1).
  float* S    = (float*)(ws + 129761280);      // 2*32*8*64*128*4  = 16,777,216
  float* P    = (float*)(ws);                  // 1024*4           = 4,096

  const int M = NBATCH * L_SEQ;  // 4096

  rmsnorm_kernel<<<M, 256, 0, stream>>>(x, norm_w, xnb);
  cvt_w1_kernel<<<DPAD, 256, 0, stream>>>(w1, w1b);
  cvt_w2_kernel<<<1024, 256, 0, stream>>>(w2, w2b);
  gemm_bt<<<dim3(DPAD / 128, M / 128), 256, 0, stream>>>(
      xnb, w1b, proj, nullptr, M, DPAD, DM);
  conv_kernel<<<M, 256, 0, stream>>>(proj, cw, cb, xhy);
  dtda_kernel<<<M * NH / 256, 256, 0, stream>>>(proj, dt_b, A_log, dAdt);
  scan_state_kernel<<<512, 1024, 0, stream>>>(proj, dAdt, xhy, S, P);
  combine_kernel<<<2048, 256, 0, stream>>>(S, P);
  scan_y_kernel<<<512, 1024, 0, stream>>>(proj, dAdt, xhy, Dv, S);
  gate_kernel<<<M * DI / 2048, 256, 0, stream>>>(xhy, proj, yb);
  gemm_bt<<<dim3(DM / 128, M / 128), 256, 0, stream>>>(
      yb, w2b, out, x, M, DM, DI);
}

// Round 4
// 243.069 us; speedup vs baseline: 6.7667x; 2.0919x over previous
//
#include <hip/hip_runtime.h>
#include <hip/hip_bf16.h>

#define L_SEQ 2048
#define DM 1024
#define DI 2048
#define DS 128
#define NH 32
#define HD 64
#define DPROJ 4384
#define DPAD 4480
#define NBATCH 2
#define NCH 8
#define CH 256
#define B_OFF 4096
#define C_OFF 4224
#define SWZ(row) ((((row) ^ ((row) >> 3)) & 7) << 4)

typedef unsigned short u16;
typedef __attribute__((ext_vector_type(8))) short short8;
typedef __attribute__((ext_vector_type(4))) float f32x4;

__device__ __forceinline__ u16 f2bf(float f) {
  union { float f; unsigned u; } c; c.f = f;
  unsigned u = c.u;
  u += 0x7fffu + ((u >> 16) & 1u);
  return (u16)(u >> 16);
}
__device__ __forceinline__ float bf2f(u16 u) {
  return __uint_as_float((unsigned)u << 16);
}
__device__ __forceinline__ float siluf(float x) {
  return x / (1.0f + expf(-x));
}

// ---------------- RMSNorm (f32 in -> bf16 out) ----------------
__global__ __launch_bounds__(256) void rmsnorm_kernel(
    const float* __restrict__ x, const float* __restrict__ w,
    u16* __restrict__ xnb) {
  int m = blockIdx.x;
  int t = threadIdx.x;
  const float* row = x + (size_t)m * DM;
  float4 v = *(const float4*)(row + t * 4);
  float ss = v.x * v.x + v.y * v.y + v.z * v.z + v.w * v.w;
#pragma unroll
  for (int o = 32; o > 0; o >>= 1) ss += __shfl_xor(ss, o);
  __shared__ float sred[4];
  if ((t & 63) == 0) sred[t >> 6] = ss;
  __syncthreads();
  ss = sred[0] + sred[1] + sred[2] + sred[3];
  float rs = rsqrtf(ss * (1.0f / DM) + 1e-6f);
  float4 wv = *(const float4*)(w + t * 4);
  ushort4 o;
  o.x = f2bf(v.x * rs * wv.x);
  o.y = f2bf(v.y * rs * wv.y);
  o.z = f2bf(v.z * rs * wv.z);
  o.w = f2bf(v.w * rs * wv.w);
  *(ushort4*)(xnb + (size_t)m * DM + t * 4) = o;
}

// ---------------- weight conversions ----------------
__global__ __launch_bounds__(256) void cvt_w1_kernel(
    const float* __restrict__ w, u16* __restrict__ o) {
  int r = blockIdx.x;
  int c = threadIdx.x * 4;
  ushort4 u;
  if (r < DPROJ) {
    float4 v = *(const float4*)(w + (size_t)r * DM + c);
    u.x = f2bf(v.x); u.y = f2bf(v.y); u.z = f2bf(v.z); u.w = f2bf(v.w);
  } else {
    u.x = 0; u.y = 0; u.z = 0; u.w = 0;
  }
  *(ushort4*)(o + (size_t)r * DM + c) = u;
}

__global__ __launch_bounds__(256) void cvt_w2_kernel(
    const float* __restrict__ w, u16* __restrict__ o) {
  size_t i = ((size_t)blockIdx.x * 256 + threadIdx.x) * 8;
  float4 v0 = *(const float4*)(w + i);
  float4 v1 = *(const float4*)(w + i + 4);
  ushort4 a, b;
  a.x = f2bf(v0.x); a.y = f2bf(v0.y); a.z = f2bf(v0.z); a.w = f2bf(v0.w);
  b.x = f2bf(v1.x); b.y = f2bf(v1.y); b.z = f2bf(v1.z); b.w = f2bf(v1.w);
  *(ushort4*)(o + i) = a;
  *(ushort4*)(o + i + 4) = b;
}

// ---------------- bf16 MFMA GEMM: C[m,n] = sum_k A[m,k]*B[n,k] (+resid) ----
__global__ __launch_bounds__(256, 2) void gemm_bt(
    const u16* __restrict__ A, const u16* __restrict__ Bw,
    float* __restrict__ C, const float* __restrict__ resid,
    int M, int N, int K) {
  __shared__ u16 lA[128 * 32];
  __shared__ u16 lB[128 * 32];
  const int tid = threadIdx.x;
  const int wv = tid >> 6, lane = tid & 63;
  const int wm = wv >> 1, wn = wv & 1;
  const int m0 = blockIdx.y * 128, n0 = blockIdx.x * 128;

  const int rowS = tid >> 2;
  const int colS = (tid & 3) * 8;
  const u16* gA0 = A + (size_t)(m0 + rowS) * K + colS;
  const u16* gA1 = A + (size_t)(m0 + rowS + 64) * K + colS;
  const u16* gB0 = Bw + (size_t)(n0 + rowS) * K + colS;
  const u16* gB1 = Bw + (size_t)(n0 + rowS + 64) * K + colS;

  f32x4 acc[4][4] = {};
  short8 ra0 = *(const short8*)gA0;
  short8 ra1 = *(const short8*)gA1;
  short8 rb0 = *(const short8*)gB0;
  short8 rb1 = *(const short8*)gB1;

  const int nk = K >> 5;
  for (int kt = 0; kt < nk; ++kt) {
    __syncthreads();
    *(short8*)&lA[tid * 8] = ra0;
    *(short8*)&lA[2048 + tid * 8] = ra1;
    *(short8*)&lB[tid * 8] = rb0;
    *(short8*)&lB[2048 + tid * 8] = rb1;
    __syncthreads();
    if (kt + 1 < nk) {
      int ko = (kt + 1) << 5;
      ra0 = *(const short8*)(gA0 + ko);
      ra1 = *(const short8*)(gA1 + ko);
      rb0 = *(const short8*)(gB0 + ko);
      rb1 = *(const short8*)(gB1 + ko);
    }
    short8 af[4], bfr[4];
    const int r = lane & 15;
    const int koff = (lane >> 4) * 8;
#pragma unroll
    for (int i = 0; i < 4; ++i)
      af[i] = *(const short8*)&lA[(wm * 64 + i * 16 + r) * 32 + koff];
#pragma unroll
    for (int j = 0; j < 4; ++j)
      bfr[j] = *(const short8*)&lB[(wn * 64 + j * 16 + r) * 32 + koff];
#pragma unroll
    for (int i = 0; i < 4; ++i)
#pragma unroll
      for (int j = 0; j < 4; ++j)
        acc[i][j] = __builtin_amdgcn_mfma_f32_16x16x32_bf16(
            af[i], bfr[j], acc[i][j], 0, 0, 0);
  }

  const int rbase = m0 + wm * 64 + (lane >> 4) * 4;
  const int cbase = n0 + wn * 64 + (lane & 15);
#pragma unroll
  for (int i = 0; i < 4; ++i) {
#pragma unroll
    for (int j = 0; j < 4; ++j) {
      int row0 = rbase + i * 16;
      int col = cbase + j * 16;
#pragma unroll
      for (int rr = 0; rr < 4; ++rr) {
        size_t o = (size_t)(row0 + rr) * N + col;
        float v = acc[i][j][rr];
        if (resid) v += resid[o];
        C[o] = v;
      }
    }
  }
}

// ---------------- depthwise causal conv (K=4) + SiLU ----------------
__global__ __launch_bounds__(256) void conv_kernel(
    const float* __restrict__ proj, const float* __restrict__ cw,
    const float* __restrict__ cb, float* __restrict__ xh) {
  int m = blockIdx.x;
  int l = m & (L_SEQ - 1);
  int c0 = threadIdx.x * 8;
  float4 wv[8];
#pragma unroll
  for (int j = 0; j < 8; ++j) wv[j] = *(const float4*)(cw + (size_t)(c0 + j) * 4);
  float acc[8];
#pragma unroll
  for (int j = 0; j < 8; ++j) acc[j] = cb[c0 + j];
#pragma unroll
  for (int k = 0; k < 4; ++k) {
    int lk = l + k - 3;
    if (lk >= 0) {
      const float* row = proj + (size_t)(m + k - 3) * DPAD + DI + c0;
      float4 r0 = *(const float4*)row;
      float4 r1 = *(const float4*)(row + 4);
      float rv[8] = {r0.x, r0.y, r0.z, r0.w, r1.x, r1.y, r1.z, r1.w};
#pragma unroll
      for (int j = 0; j < 8; ++j) {
        float wk = (k == 0) ? wv[j].x : (k == 1) ? wv[j].y : (k == 2) ? wv[j].z : wv[j].w;
        acc[j] = fmaf(rv[j], wk, acc[j]);
      }
    }
  }
  float4 o0, o1;
  o0.x = siluf(acc[0]); o0.y = siluf(acc[1]); o0.z = siluf(acc[2]); o0.w = siluf(acc[3]);
  o1.x = siluf(acc[4]); o1.y = siluf(acc[5]); o1.z = siluf(acc[6]); o1.w = siluf(acc[7]);
  float* out = xh + (size_t)m * DI + c0;
  *(float4*)out = o0;
  *(float4*)(out + 4) = o1;
}

// ---------------- dt / a = -exp(A_log)*dt ----------------
__global__ __launch_bounds__(256) void dtda_kernel(
    const float* __restrict__ proj, const float* __restrict__ dt_bias,
    const float* __restrict__ A_log, float* __restrict__ dAdt) {
  int idx = blockIdx.x * 256 + threadIdx.x;
  int m = idx >> 5, h = idx & 31;
  float raw = proj[(size_t)m * DPAD + (2 * DI + 2 * DS) + h] + dt_bias[h];
  float dt = fmaxf(raw, 0.0f) + log1pf(expf(-fabsf(raw)));
  float a = -expf(A_log[h]) * dt;
  float2 o; o.x = a; o.y = dt;
  *(float2*)(dAdt + (size_t)idx * 2) = o;
}

// ================= MFMA chunked scan =================
// Block = (b, h, ch of 256 steps); 512 threads = 8 waves; 4 serial sub-chunks
// of T=64. Per sub-chunk (row-dot-row mfma, 16x16x32 bf16):
//   G = C . B^T ; W[t,s] = (t>=s) G exp(cum t - cum s) dt[s]
//   Y = W @ X + diag(Lam) (C . H^T) ; H <- lam63*H + (Xw)^T . B
// Wave w: tile-row tw = w>>1, col-half = w&1. H lives in per-wave acc regs.

// Pass A: chunk-end state + chunk decay product.
__global__ __launch_bounds__(512) void scan_state_mfma(
    const float* __restrict__ proj, const float* __restrict__ dAdt,
    const float* __restrict__ xhy, float* __restrict__ S,
    float* __restrict__ P) {
  __shared__ u16 sBT[128 * 64];
  __shared__ u16 sXT[64 * 64];
  __shared__ u16 sXW[64 * 64];
  __shared__ float sDt[64], sCum[64], sWs[64], sLam[64];

  const int bid = blockIdx.x;
  const int ch = bid & 7, hh = (bid >> 3) & 31, b = bid >> 8;
  const int tid = threadIdx.x;
  const int w = tid >> 6, l = tid & 63;
  const int tw = w >> 1, half = w & 1;
  const int klane = (l >> 4) * 16;
  const size_t mchunk = (size_t)(b * L_SEQ + ch * CH);

  f32x4 hAcc[4] = {};
  float ctot = 0.0f;

  auto STAGE = [&](int sc) {
    const size_t m0 = mchunk + (size_t)sc * 64;
    {  // B rows -> sBT (transposed, col-pair packed)
      const int tp = tid >> 4;
      const int n0 = (tid & 15) * 8;
      const float* r0 = proj + (m0 + 2 * tp) * DPAD + B_OFF + n0;
      const float* r1 = r0 + DPAD;
      float4 a0 = *(const float4*)(r0);
      float4 a1 = *(const float4*)(r0 + 4);
      float4 a2 = *(const float4*)(r1);
      float4 a3 = *(const float4*)(r1 + 4);
      float lo[8] = {a0.x, a0.y, a0.z, a0.w, a1.x, a1.y, a1.z, a1.w};
      float hi[8] = {a2.x, a2.y, a2.z, a2.w, a3.x, a3.y, a3.z, a3.w};
#pragma unroll
      for (int q = 0; q < 8; ++q) {
        int n = n0 + q;
        unsigned v = (unsigned)f2bf(lo[q]) | ((unsigned)f2bf(hi[q]) << 16);
        *(unsigned*)((char*)sBT + ((n * 128 + 4 * tp) ^ SWZ(n))) = v;
      }
    }
    {  // x -> sXT (transposed)
      const int sx = tid >> 4;
      const int p0 = (tid & 15) * 4;
#pragma unroll
      for (int rr = 0; rr < 2; ++rr) {
        int s = sx + rr * 32;
        float4 v = *(const float4*)(xhy + (m0 + s) * DI + hh * 64 + p0);
        float arr[4] = {v.x, v.y, v.z, v.w};
#pragma unroll
        for (int i = 0; i < 4; ++i) {
          int p = p0 + i;
          *(u16*)((char*)sXT + ((p * 128 + 2 * s) ^ SWZ(p))) = f2bf(arr[i]);
        }
      }
    }
    if (tid < 64) {  // dt, cumsum of a, weights
      float2 ad = *(const float2*)(dAdt + (m0 + tid) * 64 + hh * 2);
      float a = ad.x, dtv = ad.y;
      sDt[tid] = dtv;
      float val = a;
#pragma unroll
      for (int o = 1; o < 64; o <<= 1) {
        float t2 = __shfl_up(val, o);
        if (tid >= o) val += t2;
      }
      sCum[tid] = val;
      float c63 = __shfl(val, 63);
      sWs[tid] = __expf(c63 - val) * dtv;
      sLam[tid] = __expf(val);
    }
  };

  STAGE(0);
  __syncthreads();

  for (int sc = 0; sc < 4; ++sc) {
    {  // XW build
      int p = tid >> 3, sg = tid & 7;
      int byteX = (p * 128 + sg * 16) ^ SWZ(p);
      short8 xv = *(short8*)((char*)sXT + byteX);
      short8 outp;
#pragma unroll
      for (int j = 0; j < 8; ++j)
        outp[j] = (short)f2bf(bf2f((u16)xv[j]) * sWs[sg * 8 + j]);
      *(short8*)((char*)sXW + byteX) = outp;
    }
    __syncthreads();

    {  // state mfma
      float lam63 = sLam[63];
      ctot += sCum[63];
#pragma unroll
      for (int j = 0; j < 4; ++j) {
        hAcc[j][0] *= lam63; hAcc[j][1] *= lam63;
        hAcc[j][2] *= lam63; hAcc[j][3] *= lam63;
      }
      int prow = tw * 16 + (l & 15);
      short8 aXW[2];
#pragma unroll
      for (int kk = 0; kk < 2; ++kk)
        aXW[kk] = *(short8*)((char*)sXW + ((prow * 128 + kk * 64 + klane) ^ SWZ(prow)));
#pragma unroll
      for (int j = 0; j < 4; ++j) {
        int nrow = (half * 4 + j) * 16 + (l & 15);
#pragma unroll
        for (int kk = 0; kk < 2; ++kk) {
          short8 bBT = *(short8*)((char*)sBT + ((nrow * 128 + kk * 64 + klane) ^ SWZ(nrow)));
          hAcc[j] = __builtin_amdgcn_mfma_f32_16x16x32_bf16(aXW[kk], bBT, hAcc[j], 0, 0, 0);
        }
      }
    }
    __syncthreads();
    if (sc < 3) STAGE(sc + 1);
    __syncthreads();
  }

  float* Sb = S + (size_t)((b * 32 + hh) * NCH + ch) * 8192;
  const int p0 = tw * 16 + (l >> 4) * 4;
#pragma unroll
  for (int j = 0; j < 4; ++j) {
    int n = (half * 4 + j) * 16 + (l & 15);
#pragma unroll
    for (int r = 0; r < 4; ++r)
      Sb[(p0 + r) * 128 + n] = hAcc[j][r];
  }
  if (tid == 0) P[(b * 32 + hh) * NCH + ch] = __expf(ctot);
}

// Pass 2: sequential combine; S[c] becomes H0[c].
__global__ __launch_bounds__(256) void combine_kernel(
    float* __restrict__ S, const float* __restrict__ P) {
  int tid = blockIdx.x * 256 + threadIdx.x;
  int bh = tid >> 13, pn = tid & 8191;
  size_t base = (size_t)bh * NCH * 8192 + pn;
  float E = 0.0f;
#pragma unroll
  for (int c = 0; c < NCH; ++c) {
    size_t o = base + (size_t)c * 8192;
    float Sc = S[o];
    S[o] = E;
    E = fmaf(P[bh * NCH + c], E, Sc);
  }
}

// Pass B: y from H0 (in place over xh in xhy).
__global__ __launch_bounds__(512) void scan_y_mfma(
    const float* __restrict__ proj, const float* __restrict__ dAdt,
    float* __restrict__ xhy, const float* __restrict__ Dv,
    const float* __restrict__ S) {
  __shared__ u16 sC[64 * 128];
  __shared__ u16 sB[64 * 128];
  __shared__ u16 sHb[64 * 128];
  __shared__ u16 sBT[128 * 64];
  __shared__ u16 sXT[64 * 64];
  __shared__ u16 sXW[64 * 64];
  __shared__ u16 sW[64 * 64];
  __shared__ float sDt[64], sCum[64], sWs[64], sLam[64];

  const int bid = blockIdx.x;
  const int ch = bid & 7, hh = (bid >> 3) & 31, b = bid >> 8;
  const int tid = threadIdx.x;
  const int w = tid >> 6, l = tid & 63;
  const int tw = w >> 1, half = w & 1;
  const int klane = (l >> 4) * 16;
  const float Dh = Dv[hh];
  const size_t mchunk = (size_t)(b * L_SEQ + ch * CH);

  f32x4 hAcc[4];
  {  // H0 into acc regs + sHb
    const float* Sb = S + (size_t)((b * 32 + hh) * NCH + ch) * 8192;
    const int p0 = tw * 16 + (l >> 4) * 4;
#pragma unroll
    for (int j = 0; j < 4; ++j) {
      int n = (half * 4 + j) * 16 + (l & 15);
#pragma unroll
      for (int r = 0; r < 4; ++r)
        hAcc[j][r] = Sb[(p0 + r) * 128 + n];
    }
    int p = tid >> 3, sg = tid & 7;
#pragma unroll
    for (int i = 0; i < 4; ++i) {
      float4 v = *(const float4*)(Sb + p * 128 + sg * 16 + 4 * i);
      ushort4 u;
      u.x = f2bf(v.x); u.y = f2bf(v.y); u.z = f2bf(v.z); u.w = f2bf(v.w);
      *(ushort4*)((char*)sHb + ((p * 256 + (sg * 16 + 4 * i) * 2) ^ SWZ(p))) = u;
    }
  }

  auto STAGE = [&](int sc) {
    const size_t m0 = mchunk + (size_t)sc * 64;
    {  // B, C rows + sBT
      const int tp = tid >> 4;
      const int n0 = (tid & 15) * 8;
      const float* r0 = proj + (m0 + 2 * tp) * DPAD;
      const float* r1 = r0 + DPAD;
      float4 a0 = *(const float4*)(r0 + B_OFF + n0);
      float4 a1 = *(const float4*)(r0 + B_OFF + n0 + 4);
      float4 a2 = *(const float4*)(r1 + B_OFF + n0);
      float4 a3 = *(const float4*)(r1 + B_OFF + n0 + 4);
      float4 c0 = *(const float4*)(r0 + C_OFF + n0);
      float4 c1 = *(const float4*)(r0 + C_OFF + n0 + 4);
      float4 c2 = *(const float4*)(r1 + C_OFF + n0);
      float4 c3 = *(const float4*)(r1 + C_OFF + n0 + 4);
      short8 pk;
      pk[0] = (short)f2bf(a0.x); pk[1] = (short)f2bf(a0.y);
      pk[2] = (short)f2bf(a0.z); pk[3] = (short)f2bf(a0.w);
      pk[4] = (short)f2bf(a1.x); pk[5] = (short)f2bf(a1.y);
      pk[6] = (short)f2bf(a1.z); pk[7] = (short)f2bf(a1.w);
      *(short8*)((char*)sB + ((2 * tp * 256 + n0 * 2) ^ SWZ(2 * tp))) = pk;
      pk[0] = (short)f2bf(a2.x); pk[1] = (short)f2bf(a2.y);
      pk[2] = (short)f2bf(a2.z); pk[3] = (short)f2bf(a2.w);
      pk[4] = (short)f2bf(a3.x); pk[5] = (short)f2bf(a3.y);
      pk[6] = (short)f2bf(a3.z); pk[7] = (short)f2bf(a3.w);
      *(short8*)((char*)sB + (((2 * tp + 1) * 256 + n0 * 2) ^ SWZ(2 * tp + 1))) = pk;
      pk[0] = (short)f2bf(c0.x); pk[1] = (short)f2bf(c0.y);
      pk[2] = (short)f2bf(c0.z); pk[3] = (short)f2bf(c0.w);
      pk[4] = (short)f2bf(c1.x); pk[5] = (short)f2bf(c1.y);
      pk[6] = (short)f2bf(c1.z); pk[7] = (short)f2bf(c1.w);
      *(short8*)((char*)sC + ((2 * tp * 256 + n0 * 2) ^ SWZ(2 * tp))) = pk;
      pk[0] = (short)f2bf(c2.x); pk[1] = (short)f2bf(c2.y);
      pk[2] = (short)f2bf(c2.z); pk[3] = (short)f2bf(c2.w);
      pk[4] = (short)f2bf(c3.x); pk[5] = (short)f2bf(c3.y);
      pk[6] = (short)f2bf(c3.z); pk[7] = (short)f2bf(c3.w);
      *(short8*)((char*)sC + (((2 * tp + 1) * 256 + n0 * 2) ^ SWZ(2 * tp + 1))) = pk;
      float lo[8] = {a0.x, a0.y, a0.z, a0.w, a1.x, a1.y, a1.z, a1.w};
      float hi[8] = {a2.x, a2.y, a2.z, a2.w, a3.x, a3.y, a3.z, a3.w};
#pragma unroll
      for (int q = 0; q < 8; ++q) {
        int n = n0 + q;
        unsigned v = (unsigned)f2bf(lo[q]) | ((unsigned)f2bf(hi[q]) << 16);
        *(unsigned*)((char*)sBT + ((n * 128 + 4 * tp) ^ SWZ(n))) = v;
      }
    }
    {  // x -> sXT
      const int sx = tid >> 4;
      const int p0 = (tid & 15) * 4;
#pragma unroll
      for (int rr = 0; rr < 2; ++rr) {
        int s = sx + rr * 32;
        float4 v = *(const float4*)(xhy + (m0 + s) * DI + hh * 64 + p0);
        float arr[4] = {v.x, v.y, v.z, v.w};
#pragma unroll
        for (int i = 0; i < 4; ++i) {
          int p = p0 + i;
          *(u16*)((char*)sXT + ((p * 128 + 2 * s) ^ SWZ(p))) = f2bf(arr[i]);
        }
      }
    }
    if (tid < 64) {
      float2 ad = *(const float2*)(dAdt + (m0 + tid) * 64 + hh * 2);
      float a = ad.x, dtv = ad.y;
      sDt[tid] = dtv;
      float val = a;
#pragma unroll
      for (int o = 1; o < 64; o <<= 1) {
        float t2 = __shfl_up(val, o);
        if (tid >= o) val += t2;
      }
      sCum[tid] = val;
      float c63 = __shfl(val, 63);
      sWs[tid] = __expf(c63 - val) * dtv;
      sLam[tid] = __expf(val);
    }
  };

  STAGE(0);
  __syncthreads();

  for (int sc = 0; sc < 4; ++sc) {
    const size_t m0 = mchunk + (size_t)sc * 64;
    {  // XW build
      int p = tid >> 3, sg = tid & 7;
      int byteX = (p * 128 + sg * 16) ^ SWZ(p);
      short8 xv = *(short8*)((char*)sXT + byteX);
      short8 outp;
#pragma unroll
      for (int j = 0; j < 8; ++j)
        outp[j] = (short)f2bf(bf2f((u16)xv[j]) * sWs[sg * 8 + j]);
      *(short8*)((char*)sXW + byteX) = outp;
    }
    __syncthreads();

    const int trow = tw * 16 + (l & 15);
    short8 aC[4];
#pragma unroll
    for (int kk = 0; kk < 4; ++kk)
      aC[kk] = *(short8*)((char*)sC + ((trow * 256 + kk * 64 + klane) ^ SWZ(trow)));

    {  // G + W write
      f32x4 g[2] = {};
#pragma unroll
      for (int sv2 = 0; sv2 < 2; ++sv2) {
        int srow = (half * 2 + sv2) * 16 + (l & 15);
#pragma unroll
        for (int kk = 0; kk < 4; ++kk) {
          short8 bB = *(short8*)((char*)sB + ((srow * 256 + kk * 64 + klane) ^ SWZ(srow)));
          g[sv2] = __builtin_amdgcn_mfma_f32_16x16x32_bf16(aC[kk], bB, g[sv2], 0, 0, 0);
        }
      }
#pragma unroll
      for (int sv2 = 0; sv2 < 2; ++sv2) {
        int s = (half * 2 + sv2) * 16 + (l & 15);
        float dts = sDt[s], cums = sCum[s];
#pragma unroll
        for (int r = 0; r < 4; ++r) {
          int t = tw * 16 + (l >> 4) * 4 + r;
          float v = (t >= s) ? g[sv2][r] * __expf(sCum[t] - cums) * dts : 0.0f;
          *(u16*)((char*)sW + ((t * 128 + 2 * s) ^ SWZ(t))) = f2bf(v);
        }
      }
    }
    __syncthreads();

    f32x4 y1[2] = {}, y2[2] = {};
    float lamv[4], lam63 = sLam[63];
#pragma unroll
    for (int r = 0; r < 4; ++r) lamv[r] = sLam[tw * 16 + (l >> 4) * 4 + r];
    {
      short8 aW[2];
#pragma unroll
      for (int kk = 0; kk < 2; ++kk)
        aW[kk] = *(short8*)((char*)sW + ((trow * 128 + kk * 64 + klane) ^ SWZ(trow)));
#pragma unroll
      for (int pv2 = 0; pv2 < 2; ++pv2) {
        int prow = (half * 2 + pv2) * 16 + (l & 15);
#pragma unroll
        for (int kk = 0; kk < 2; ++kk) {
          short8 bX = *(short8*)((char*)sXT + ((prow * 128 + kk * 64 + klane) ^ SWZ(prow)));
          y1[pv2] = __builtin_amdgcn_mfma_f32_16x16x32_bf16(aW[kk], bX, y1[pv2], 0, 0, 0);
        }
#pragma unroll
        for (int kk = 0; kk < 4; ++kk) {
          short8 bH = *(short8*)((char*)sHb + ((prow * 256 + kk * 64 + klane) ^ SWZ(prow)));
          y2[pv2] = __builtin_amdgcn_mfma_f32_16x16x32_bf16(aC[kk], bH, y2[pv2], 0, 0, 0);
        }
      }
      // state update
#pragma unroll
      for (int j = 0; j < 4; ++j) {
        hAcc[j][0] *= lam63; hAcc[j][1] *= lam63;
        hAcc[j][2] *= lam63; hAcc[j][3] *= lam63;
      }
      short8 aXW[2];
#pragma unroll
      for (int kk = 0; kk < 2; ++kk)
        aXW[kk] = *(short8*)((char*)sXW + ((trow * 128 + kk * 64 + klane) ^ SWZ(trow)));
#pragma unroll
      for (int j = 0; j < 4; ++j) {
        int nrow = (half * 4 + j) * 16 + (l & 15);
#pragma unroll
        for (int kk = 0; kk < 2; ++kk) {
          short8 bBT = *(short8*)((char*)sBT + ((nrow * 128 + kk * 64 + klane) ^ SWZ(nrow)));
          hAcc[j] = __builtin_amdgcn_mfma_f32_16x16x32_bf16(aXW[kk], bBT, hAcc[j], 0, 0, 0);
        }
      }
    }
    __syncthreads();

    {  // Hb write + y epilogue + next stage
#pragma unroll
      for (int j = 0; j < 4; ++j) {
        int n = (half * 4 + j) * 16 + (l & 15);
#pragma unroll
        for (int r = 0; r < 4; ++r) {
          int p = tw * 16 + (l >> 4) * 4 + r;
          *(u16*)((char*)sHb + ((p * 256 + 2 * n) ^ SWZ(p))) = f2bf(hAcc[j][r]);
        }
      }
#pragma unroll
      for (int pv2 = 0; pv2 < 2; ++pv2) {
        int p = (half * 2 + pv2) * 16 + (l & 15);
#pragma unroll
        for (int r = 0; r < 4; ++r) {
          int t = tw * 16 + (l >> 4) * 4 + r;
          size_t ga = (m0 + t) * DI + hh * 64 + p;
          float xv = xhy[ga];
          xhy[ga] = y1[pv2][r] + lamv[r] * y2[pv2][r] + Dh * xv;
        }
      }
      if (sc < 3) STAGE(sc + 1);
    }
    __syncthreads();
  }
}

// ---------------- gating: yb = bf16(y * silu(z)) ----------------
__global__ __launch_bounds__(256) void gate_kernel(
    const float* __restrict__ xhy, const float* __restrict__ proj,
    u16* __restrict__ yb) {
  size_t i0 = ((size_t)blockIdx.x * 256 + threadIdx.x) * 8;
  size_t m = i0 >> 11;
  int c = (int)(i0 & 2047);
  float4 y0 = *(const float4*)(xhy + i0);
  float4 y1 = *(const float4*)(xhy + i0 + 4);
  const float* zp = proj + m * DPAD + c;
  float4 z0 = *(const float4*)zp;
  float4 z1 = *(const float4*)(zp + 4);
  ushort4 a, bq;
  a.x = f2bf(y0.x * siluf(z0.x));
  a.y = f2bf(y0.y * siluf(z0.y));
  a.z = f2bf(y0.z * siluf(z0.z));
  a.w = f2bf(y0.w * siluf(z0.w));
  bq.x = f2bf(y1.x * siluf(z1.x));
  bq.y = f2bf(y1.y * siluf(z1.y));
  bq.z = f2bf(y1.z * siluf(z1.z));
  bq.w = f2bf(y1.w * siluf(z1.w));
  *(ushort4*)(yb + i0) = a;
  *(ushort4*)(yb + i0 + 4) = bq;
}

extern "C" void kernel_launch(void* const* d_in, const int* in_sizes, int n_in,
                              void* d_out, int out_size, void* d_ws, size_t ws_size,
                              hipStream_t stream) {
  const float* x      = (const float*)d_in[0];
  const float* norm_w = (const float*)d_in[1];
  const float* w1     = (const float*)d_in[2];
  const float* cw     = (const float*)d_in[3];
  const float* cb     = (const float*)d_in[4];
  const float* A_log  = (const float*)d_in[5];
  const float* Dv     = (const float*)d_in[6];
  const float* dt_b   = (const float*)d_in[7];
  const float* w2     = (const float*)d_in[8];
  float* out = (float*)d_out;

  char* ws = (char*)d_ws;
  u16*   xnb  = (u16*)(ws);
  u16*   w1b  = (u16*)(ws + 8388608);
  u16*   w2b  = (u16*)(ws + 17563648);
  float* proj = (float*)(ws + 21757952);
  float* xhy  = (float*)(ws + 95158272);
  float* dAdt = (float*)(ws + 128712704);
  u16*   yb   = (u16*)(ws + 129761280);
  float* S    = (float*)(ws + 129761280);   // aliases yb (dead until gate)
  float* P    = (float*)(ws);               // aliases xnb (dead after gemm1)

  const int M = NBATCH * L_SEQ;

  rmsnorm_kernel<<<M, 256, 0, stream>>>(x, norm_w, xnb);
  cvt_w1_kernel<<<DPAD, 256, 0, stream>>>(w1, w1b);
  cvt_w2_kernel<<<1024, 256, 0, stream>>>(w2, w2b);
  gemm_bt<<<dim3(DPAD / 128, M / 128), 256, 0, stream>>>(
      xnb, w1b, proj, nullptr, M, DPAD, DM);
  conv_kernel<<<M, 256, 0, stream>>>(proj, cw, cb, xhy);
  dtda_kernel<<<M * NH / 256, 256, 0, stream>>>(proj, dt_b, A_log, dAdt);
  scan_state_mfma<<<512, 512, 0, stream>>>(proj, dAdt, xhy, S, P);
  combine_kernel<<<2048, 256, 0, stream>>>(S, P);
  scan_y_mfma<<<512, 512, 0, stream>>>(proj, dAdt, xhy, Dv, S);
  gate_kernel<<<M * DI / 2048, 256, 0, stream>>>(xhy, proj, yb);
  gemm_bt<<<dim3(DM / 128, M / 128), 256, 0, stream>>>(
      yb, w2b, out, x, M, DM, DI);
}